// Round 1
// baseline (871.530 us; speedup 1.0000x reference)
//
#include <hip/hip_runtime.h>
#include <hip/hip_bf16.h>
#include <math.h>

#define DIM   512
#define HIDW  256
#define ATTW  128
#define MAXC  50
#define BLK   256
#define BUFW  136    // K/Q/corr/K2 row stride (272B, 16B-aligned, 68dw = +4 banks/row)
#define HL2   264    // hidden row stride for MFMA kernel (528B, 16B-aligned, +4 banks/row)
#define PAW   72     // pa / vt row stride (144B, 16B-aligned, +4 banks/row)
#define SB_W  52
#define CH    10
#define SCL   0.08838834764831845f  // 1/sqrt(128)

typedef float f32x4 __attribute__((ext_vector_type(4)));
typedef short s16x8 __attribute__((ext_vector_type(8)));

__device__ __forceinline__ float bf2f(ushort u){ union{unsigned i;float f;}v; v.i=((unsigned)u)<<16; return v.f; }
__device__ __forceinline__ ushort f2bf(float f){
  union{float f;unsigned i;}v; v.f=f;
  unsigned r = v.i + 0x7fffu + ((v.i>>16)&1u);
  return (ushort)(r>>16);
}
__device__ __forceinline__ s16x8 ldfrag(const ushort* p){ s16x8 v; __builtin_memcpy(&v, p, 16); return v; }
__device__ __forceinline__ f32x4 mfma16(s16x8 a, s16x8 b, f32x4 c){
  return __builtin_amdgcn_mfma_f32_16x16x32_bf16(a, b, c, 0, 0, 0);
}

template<bool F32>
__device__ __forceinline__ float ld(const void* p, int i){
  if (F32) return ((const float*)p)[i];
  return bf2f(((const ushort*)p)[i]);
}

struct P27 {
  const void *molA, *nodeH; const int* counts;
  const void *wq1,*bq1,*wq2,*bq2, *wk1,*bk1,*wk2,*bk2, *wv1,*bv1,*wv2,*bv2;
  const void *uk1,*ubk1,*uk2,*ubk2, *uq1,*ubq1,*uq2,*ubq2;
  const void *cs1,*bcs1,*cs2,*bcs2;
  void* out;
};

// workspace: wsInt[0]=f32flag, wsInt[4..4+nb) offsets; wt (bf16) at byte 8704
#define O_WK1T 0
#define O_WQ1T 131072
#define O_WV1T 262144
#define O_WK2T 393216
#define O_WQ2T 425984
#define O_WV2T 458752
#define O_UK1T 491520
#define O_UK2T 524288
#define WT_ELEMS   557056
#define O_UQ1TT 557056
#define O_UQ2TT 688128
#define WT2_ELEMS  720896
#define WT_T2ELEMS 393216
#define WT_BYTE_OFF 8704
#define Q2_BYTE_OFF (WT_BYTE_OFF + WT2_ELEMS*2)   // 1450496, 16B-aligned

// ---------- prep: dtype detect + exclusive scan (VERBATIM, validated) ----------
__global__ void prep_kernel(const ushort* __restrict__ molAu,
                            const int* __restrict__ counts, int nb,
                            int* __restrict__ wsInt)
{
  __shared__ int part[BLK];
  __shared__ int cnt;
  const int t = threadIdx.x;
  if (t == 0) cnt = 0;
  __syncthreads();
  int e = (molAu[t] >> 7) & 0xFF;
  if (e >= 100 && e <= 140) atomicAdd(&cnt, 1);
  const int per = (nb + BLK - 1) / BLK;
  int s = 0;
  for (int i = 0; i < per; i++) { int idx = t*per + i; if (idx < nb) s += counts[idx]; }
  part[t] = s;
  __syncthreads();
  if (t == 0) {
    int run = 0;
    for (int i = 0; i < BLK; i++) { int v = part[i]; part[i] = run; run += v; }
    wsInt[0] = (cnt >= 220) ? 0 : 1;        // 0 = bf16 inputs, 1 = f32 inputs
  }
  __syncthreads();
  int run = part[t];
  for (int i = 0; i < per; i++) {
    int idx = t*per + i;
    if (idx < nb) { wsInt[4 + idx] = run; run += counts[idx]; }
  }
}

// ---------- prep: transpose+convert weight matrices -> bf16 (bounds-guarded) ----------
__global__ void transpose_wt(P27 P, const int* __restrict__ wsInt,
                             ushort* __restrict__ wt, unsigned long long cap_elems)
{
  unsigned i = blockIdx.x*BLK + threadIdx.x;
  if (i >= WT2_ELEMS) return;
  if ((unsigned long long)i >= cap_elems) return;
  const int f32m = wsInt[0];
  const void* src; int idx;
  if (i < O_WK2T) {                 // w1: (512x256) -> (256x512)
    int m = i / 131072; int j = i - m*131072;
    src = (m==0) ? P.wk1 : ((m==1) ? P.wq1 : P.wv1);
    int n = j >> 9, k = j & 511;
    idx = k*HIDW + n;
  } else if (i < O_UK1T) {          // w2: (256x128) -> (128x256)
    int m = (i - O_WK2T) / 32768; int j = (i - O_WK2T) - m*32768;
    src = (m==0) ? P.wk2 : ((m==1) ? P.wq2 : P.wv2);
    int n = j >> 8, k = j & 255;
    idx = k*ATTW + n;
  } else if (i < O_UK2T) {          // uk1: (128x256) -> (256x128)
    int j = i - O_UK1T; src = P.uk1;
    int n = j >> 7, k = j & 127;
    idx = k*HIDW + n;
  } else if (i < O_UQ1TT) {         // uk2: (256x128) -> (128x256)
    int j = i - O_UK2T; src = P.uk2;
    int n = j >> 8, k = j & 255;
    idx = k*ATTW + n;
  } else if (i < O_UQ2TT) {         // uq1: (512x256) -> (256x512)
    int j = i - O_UQ1TT; src = P.uq1;
    int n = j >> 9, k = j & 511;
    idx = k*HIDW + n;
  } else {                          // uq2: (256x128) -> (128x256)
    int j = i - O_UQ2TT; src = P.uq2;
    int n = j >> 8, k = j & 255;
    idx = k*ATTW + n;
  }
  float v = f32m ? ((const float*)src)[idx] : bf2f(((const ushort*)src)[idx]);
  wt[i] = f2bf(v);
}

// ---------- MFMA stage1: X rows (pads=0) @ W1t(256x512) + b1, relu -> hl ----------
template<bool F32>
__device__ __forceinline__ void stage1_mfma(const void* __restrict__ X, int xb, int c,
                                            const ushort* __restrict__ Wt,
                                            const void* __restrict__ Bv,
                                            ushort* __restrict__ hl, int hls, int t,
                                            int wlim)
{
  const int w = t >> 6, L = t & 63, quad = L >> 4, l16 = L & 15;
  f32x4 acc[4][4];
#pragma unroll
  for (int i = 0; i < 4; i++)
#pragma unroll
    for (int j = 0; j < 4; j++) acc[i][j] = (f32x4){0.f,0.f,0.f,0.f};

  bool va[4]; int rr[4];
#pragma unroll
  for (int mt = 0; mt < 4; mt++) {
    int row = mt*16 + l16;
    va[mt] = (row < c);
    rr[mt] = va[mt] ? row : 0;
  }
  const ushort* pB = Wt + (size_t)(w*64 + l16)*DIM + quad*8;

  for (int k0 = 0; k0 < DIM; k0 += 32) {
    s16x8 a[4];
#pragma unroll
    for (int mt = 0; mt < 4; mt++) {
      s16x8 z = {};
      if (va[mt]) {
        if (F32) {
          const float* xp = (const float*)X + xb + rr[mt]*DIM + k0 + quad*8;
          f32x4 v0, v1;
          __builtin_memcpy(&v0, xp, 16);
          __builtin_memcpy(&v1, xp+4, 16);
          s16x8 v;
#pragma unroll
          for (int j = 0; j < 4; j++) { v[j] = (short)f2bf(v0[j]); v[4+j] = (short)f2bf(v1[j]); }
          a[mt] = v;
        } else {
          a[mt] = ldfrag((const ushort*)X + xb + rr[mt]*DIM + k0 + quad*8);
        }
      } else a[mt] = z;
    }
#pragma unroll
    for (int nt = 0; nt < 4; nt++) {
      s16x8 b = ldfrag(pB + (size_t)nt*16*DIM + k0);
#pragma unroll
      for (int mt = 0; mt < 4; mt++)
        acc[mt][nt] = mfma16(a[mt], b, acc[mt][nt]);
    }
  }
#pragma unroll
  for (int nt = 0; nt < 4; nt++) {
    int col = w*64 + nt*16 + l16;
    float bb = ld<F32>(Bv, col);
#pragma unroll
    for (int mt = 0; mt < 4; mt++)
#pragma unroll
      for (int r = 0; r < 4; r++) {
        int row = mt*16 + quad*4 + r;
        if (row < wlim)
          hl[row*hls + col] = f2bf(fmaxf(acc[mt][nt][r] + bb, 0.f));
      }
  }
}

// ---------- MFMA stage2: hl(50 x HL2) @ W2t(128x256) + b2 -> dst(50 x BUFW) ----------
template<bool F32>
__device__ __forceinline__ void stage2_mfma(const ushort* __restrict__ hl,
                                            const ushort* __restrict__ W2t,
                                            const void* __restrict__ Bv,
                                            ushort* __restrict__ dst, int t)
{
  const int w = t >> 6, L = t & 63, quad = L >> 4, l16 = L & 15;
  f32x4 acc[4][2];
#pragma unroll
  for (int i = 0; i < 4; i++) { acc[i][0] = (f32x4){0.f,0.f,0.f,0.f}; acc[i][1] = (f32x4){0.f,0.f,0.f,0.f}; }
  const ushort* pB = W2t + (size_t)(w*32 + l16)*HIDW + quad*8;
  for (int k0 = 0; k0 < HIDW; k0 += 32) {
    s16x8 b0 = ldfrag(pB + k0);
    s16x8 b1 = ldfrag(pB + (size_t)16*HIDW + k0);
#pragma unroll
    for (int mt = 0; mt < 4; mt++) {
      s16x8 a = ldfrag(hl + (mt*16 + l16)*HL2 + k0 + quad*8);  // rows>=50 read junk, discarded
      acc[mt][0] = mfma16(a, b0, acc[mt][0]);
      acc[mt][1] = mfma16(a, b1, acc[mt][1]);
    }
  }
#pragma unroll
  for (int nt = 0; nt < 2; nt++) {
    int col = w*32 + nt*16 + l16;
    float bb = ld<F32>(Bv, col);
#pragma unroll
    for (int mt = 0; mt < 4; mt++)
#pragma unroll
      for (int r = 0; r < 4; r++) {
        int row = mt*16 + quad*4 + r;
        if (row < MAXC)
          dst[row*BUFW + col] = f2bf(acc[mt][nt][r] + bb);
      }
  }
}

// ---------- MFMA stage2-V: hl @ W2t + b2 -> vt TRANSPOSED (vt aliases hl!) ----------
template<bool F32>
__device__ __forceinline__ void stage2v_vt(const ushort* __restrict__ hl,
                                           const ushort* __restrict__ W2t,
                                           const void* __restrict__ Bv,
                                           ushort* __restrict__ vt, int t)
{
  const int w = t >> 6, L = t & 63, quad = L >> 4, l16 = L & 15;
  f32x4 acc[4][2];
#pragma unroll
  for (int i = 0; i < 4; i++) { acc[i][0] = (f32x4){0.f,0.f,0.f,0.f}; acc[i][1] = (f32x4){0.f,0.f,0.f,0.f}; }
  const ushort* pB = W2t + (size_t)(w*32 + l16)*HIDW + quad*8;
  for (int k0 = 0; k0 < HIDW; k0 += 32) {
    s16x8 b0 = ldfrag(pB + k0);
    s16x8 b1 = ldfrag(pB + (size_t)16*HIDW + k0);
#pragma unroll
    for (int mt = 0; mt < 4; mt++) {
      s16x8 a = ldfrag(hl + (mt*16 + l16)*HL2 + k0 + quad*8);
      acc[mt][0] = mfma16(a, b0, acc[mt][0]);
      acc[mt][1] = mfma16(a, b1, acc[mt][1]);
    }
  }
  __syncthreads();   // all hl reads complete before overwriting (vt aliases hl region)
#pragma unroll
  for (int nt = 0; nt < 2; nt++) {
    int col = w*32 + nt*16 + l16;
    float bb = ld<F32>(Bv, col);
#pragma unroll
    for (int mt = 0; mt < 4; mt++)
#pragma unroll
      for (int r = 0; r < 4; r++) {
        int row = mt*16 + quad*4 + r;
        if (row < MAXC)
          vt[col*PAW + row] = f2bf(acc[mt][nt][r] + bb);
      }
  }
  // zero k-dim pad rows [50,64) for every col (junk here would poison corr via NaN)
  for (int idx = t; idx < ATTW*(64-MAXC); idx += BLK) {
    int cc = idx / (64-MAXC), rr2 = MAXC + idx % (64-MAXC);
    vt[cc*PAW + rr2] = 0;
  }
}

// ---------- MFMA K2-stage1: src(50 x BUFW) @ W1t(256x128) + b, relu -> hl ----------
template<bool F32>
__device__ __forceinline__ void s1l_mfma(const ushort* __restrict__ src,
                                         const ushort* __restrict__ W1t,
                                         const void* __restrict__ Bv,
                                         ushort* __restrict__ hl, int t)
{
  const int w = t >> 6, L = t & 63, quad = L >> 4, l16 = L & 15;
  f32x4 acc[4][4];
#pragma unroll
  for (int i = 0; i < 4; i++)
#pragma unroll
    for (int j = 0; j < 4; j++) acc[i][j] = (f32x4){0.f,0.f,0.f,0.f};
  const ushort* pB = W1t + (size_t)(w*64 + l16)*ATTW + quad*8;
  for (int k0 = 0; k0 < ATTW; k0 += 32) {
    s16x8 b[4];
#pragma unroll
    for (int nt = 0; nt < 4; nt++) b[nt] = ldfrag(pB + (size_t)nt*16*ATTW + k0);
#pragma unroll
    for (int mt = 0; mt < 4; mt++) {
      s16x8 a = ldfrag(src + (mt*16 + l16)*BUFW + k0 + quad*8);  // rows>=50 junk, discarded
#pragma unroll
      for (int nt = 0; nt < 4; nt++)
        acc[mt][nt] = mfma16(a, b[nt], acc[mt][nt]);
    }
  }
#pragma unroll
  for (int nt = 0; nt < 4; nt++) {
    int col = w*64 + nt*16 + l16;
    float bb = ld<F32>(Bv, col);
#pragma unroll
    for (int mt = 0; mt < 4; mt++)
#pragma unroll
      for (int r = 0; r < 4; r++) {
        int row = mt*16 + quad*4 + r;
        if (row < MAXC)
          hl[row*HL2 + col] = f2bf(fmaxf(acc[mt][nt][r] + bb, 0.f));
      }
  }
}

// ---------- MFMA scores: K(buf0) @ Q(buf1)^T -> sb (masked, scaled) ----------
__device__ __forceinline__ void scores_mfma(const ushort* __restrict__ buf0,
                                            const ushort* __restrict__ buf1,
                                            float* __restrict__ sb, int c, int t)
{
  const int w = t >> 6, L = t & 63, quad = L >> 4, l16 = L & 15;
  f32x4 acc[4];
#pragma unroll
  for (int i = 0; i < 4; i++) acc[i] = (f32x4){0.f,0.f,0.f,0.f};
  const ushort* pB = buf1 + (w*16 + l16)*BUFW + quad*8;   // wave w -> cols w*16..w*16+15
  for (int k0 = 0; k0 < ATTW; k0 += 32) {
    s16x8 b = ldfrag(pB + k0);
#pragma unroll
    for (int mt = 0; mt < 4; mt++) {
      s16x8 a = ldfrag(buf0 + (mt*16 + l16)*BUFW + k0 + quad*8);
      acc[mt] = mfma16(a, b, acc[mt]);
    }
  }
  const int col = w*16 + l16;
#pragma unroll
  for (int mt = 0; mt < 4; mt++)
#pragma unroll
    for (int r = 0; r < 4; r++) {
      int row = mt*16 + quad*4 + r;
      if (row < MAXC && col < MAXC)
        sb[row*SB_W + col] = (row < c && col < c) ? acc[mt][r]*SCL : -1e9f*SCL;
    }
}

// ---------- parallel softmax (4 lanes/row) + P->bf16 into pa ----------
__device__ __forceinline__ void softmax_pa(float* __restrict__ sb,
                                           ushort* __restrict__ pa, int c, int t)
{
  const int m = t >> 2, j = t & 3;
  if (m < MAXC) {
    float* row = sb + m*SB_W;
    float mx = -3.4e38f;
    for (int n = j; n < MAXC; n += 4) mx = fmaxf(mx, row[n]);
    mx = fmaxf(mx, __shfl_xor(mx, 1));
    mx = fmaxf(mx, __shfl_xor(mx, 2));
    float sum = 0.f;
    for (int n = j; n < MAXC; n += 4) { float e = expf(row[n] - mx); row[n] = e; sum += e; }
    sum += __shfl_xor(sum, 1);
    sum += __shfl_xor(sum, 2);
    float inv = 1.f / sum;
    for (int n = j; n < 64; n += 4)
      pa[m*PAW + n] = (n < MAXC) ? f2bf(row[n] * inv) : (ushort)0;
  }
}

// ---------- MFMA corr: pa(P bf16) @ vt(V^T) -> dst(50 x BUFW) ----------
__device__ __forceinline__ void corr_mfma(const ushort* __restrict__ pa,
                                          const ushort* __restrict__ vt,
                                          ushort* __restrict__ dst, int t)
{
  const int w = t >> 6, L = t & 63, quad = L >> 4, l16 = L & 15;
  f32x4 acc[4][2];
#pragma unroll
  for (int i = 0; i < 4; i++) { acc[i][0] = (f32x4){0.f,0.f,0.f,0.f}; acc[i][1] = (f32x4){0.f,0.f,0.f,0.f}; }
  const ushort* pB = vt + (size_t)(w*32 + l16)*PAW + quad*8;
  for (int k0 = 0; k0 < 64; k0 += 32) {
    s16x8 b0 = ldfrag(pB + k0);
    s16x8 b1 = ldfrag(pB + (size_t)16*PAW + k0);
#pragma unroll
    for (int mt = 0; mt < 4; mt++) {
      s16x8 a = ldfrag(pa + (mt*16 + l16)*PAW + k0 + quad*8);   // rows>=50 junk, discarded
      acc[mt][0] = mfma16(a, b0, acc[mt][0]);
      acc[mt][1] = mfma16(a, b1, acc[mt][1]);
    }
  }
#pragma unroll
  for (int nt = 0; nt < 2; nt++) {
    int col = w*32 + nt*16 + l16;
#pragma unroll
    for (int mt = 0; mt < 4; mt++)
#pragma unroll
      for (int r = 0; r < 4; r++) {
        int row = mt*16 + quad*4 + r;
        if (row < MAXC)
          dst[row*BUFW + col] = f2bf(acc[mt][nt][r]);
      }
  }
}

// ---------- Q2 pre-kernel: molA @ uq1t relu @ uq2t -> q2ws (one-shot GEMM) ----------
template<bool F32>
__device__ void q2_body(const P27& P, const ushort* __restrict__ wt,
                        float* __restrict__ q2ws, int b0, int rows, int t,
                        ushort* __restrict__ hq)
{
  stage1_mfma<F32>(P.molA, b0*DIM, rows, wt + O_UQ1TT, P.ubq1, hq, HL2, t, 64);
  __syncthreads();
  const int w = t >> 6, L = t & 63, quad = L >> 4, l16 = L & 15;
  f32x4 acc[4][2];
#pragma unroll
  for (int i = 0; i < 4; i++) { acc[i][0] = (f32x4){0.f,0.f,0.f,0.f}; acc[i][1] = (f32x4){0.f,0.f,0.f,0.f}; }
  const ushort* pB = wt + O_UQ2TT + (size_t)(w*32 + l16)*HIDW + quad*8;
  for (int k0 = 0; k0 < HIDW; k0 += 32) {
    s16x8 bf0 = ldfrag(pB + k0);
    s16x8 bf1 = ldfrag(pB + (size_t)16*HIDW + k0);
#pragma unroll
    for (int mt = 0; mt < 4; mt++) {
      s16x8 a = ldfrag(hq + (mt*16 + l16)*HL2 + k0 + quad*8);
      acc[mt][0] = mfma16(a, bf0, acc[mt][0]);
      acc[mt][1] = mfma16(a, bf1, acc[mt][1]);
    }
  }
#pragma unroll
  for (int nt = 0; nt < 2; nt++) {
    int col = w*32 + nt*16 + l16;
    float bb = ld<F32>(P.ubq2, col);
#pragma unroll
    for (int mt = 0; mt < 4; mt++)
#pragma unroll
      for (int r = 0; r < 4; r++) {
        int row = mt*16 + quad*4 + r;
        if (row < rows)
          q2ws[(size_t)(b0 + row)*ATTW + col] = acc[mt][nt][r] + bb;
      }
  }
}

__global__ void q2_kernel(P27 P, const int* __restrict__ wsInt,
                          const ushort* __restrict__ wt, float* __restrict__ q2ws, int nb)
{
  __shared__ __align__(16) ushort hq[64*HL2];
  const int t = threadIdx.x;
  const int b0 = blockIdx.x*64;
  int rows = nb - b0; if (rows > 64) rows = 64;
  if (rows <= 0) return;
  if (wsInt[0]) q2_body<true >(P, wt, q2ws, b0, rows, t, hq);
  else          q2_body<false>(P, wt, q2ws, b0, rows, t, hq);
}

// ================= tier-0/1 body: MFMA everywhere, hoisted Q2 optional =================
template<bool F32>
__device__ void body_v3(const P27& P, int b, int t, char* smem,
                        int offset, int c, const ushort* __restrict__ wt,
                        const float* __restrict__ q2ws, int useQ2)
{
  ushort* hl   = (ushort*)smem;                 // 26400 B ; vt aliases after stage2-V
  ushort* vt   = (ushort*)smem;                 // 128 x PAW = 18432 B
  ushort* buf0 = (ushort*)(smem + 26400);       // 13600 B
  ushort* buf1 = (ushort*)(smem + 40000);       // 13600 B ; pa aliases after softmax
  ushort* pa   = buf1;                          // 64 x PAW = 9216 B
  float*  sb   = (float*)(smem + 53600);        // 2600 f32 = 10400 B (ends 64000)
  float* q2h  = sb;          // head aliases: live only after attn state dead
  float* q2   = sb + 256;
  float* lgt  = sb + 384;
  float* selh = sb + 448;

  const int xb = offset * DIM;

  // K -> buf0
  stage1_mfma<F32>(P.nodeH, xb, c, wt + O_WK1T, P.bk1, hl, HL2, t, MAXC);
  __syncthreads();
  stage2_mfma<F32>(hl, wt + O_WK2T, P.bk2, buf0, t);
  __syncthreads();
  // Q -> buf1
  stage1_mfma<F32>(P.nodeH, xb, c, wt + O_WQ1T, P.bq1, hl, HL2, t, MAXC);
  __syncthreads();
  stage2_mfma<F32>(hl, wt + O_WQ2T, P.bq2, buf1, t);
  __syncthreads();

  // scores via MFMA -> sb
  scores_mfma(buf0, buf1, sb, c, t);
  __syncthreads();
  // softmax (4 lanes/row) + P->bf16 into pa (overwrites buf1=Q, dead)
  softmax_pa(sb, pa, c, t);
  __syncthreads();

  // V -> vt (transposed; vt aliases hl, internal barrier inside)
  stage1_mfma<F32>(P.nodeH, xb, c, wt + O_WV1T, P.bv1, hl, HL2, t, MAXC);
  __syncthreads();
  stage2v_vt<F32>(hl, wt + O_WV2T, P.bv2, vt, t);
  __syncthreads();

  // corr = P @ V via MFMA -> buf0 (K dead)
  corr_mfma(pa, vt, buf0, t);
  __syncthreads();

  // K2 (both stages MFMA): corr(buf0) -> hl -> buf1 (pa dead)
  s1l_mfma<F32>(buf0, wt + O_UK1T, P.ubk1, hl, t);
  __syncthreads();
  stage2_mfma<F32>(hl, wt + O_UK2T, P.ubk2, buf1, t);
  __syncthreads();

  // Q2: hoisted (read precomputed) or inline fallback
  if (useQ2) {
    if (t < ATTW) q2[t] = q2ws[(size_t)b*ATTW + t];
  } else {
    float a = 0.f;
    for (int k = 0; k < DIM; k++)
      a += ld<F32>(P.molA, b*DIM + k) * ld<F32>(P.uq1, k*HIDW + t);
    q2h[t] = fmaxf(a + ld<F32>(P.ubq1, t), 0.f);
    __syncthreads();
    if (t < ATTW) {
      float a2 = 0.f;
      for (int k = 0; k < HIDW; k++)
        a2 += q2h[k] * ld<F32>(P.uq2, k*ATTW + t);
      q2[t] = a2 + ld<F32>(P.ubq2, t);
    }
  }
  __syncthreads();
  if (t < MAXC) {
    float s = 0.f;
    for (int k = 0; k < ATTW; k++)
      s += bf2f(buf1[t*BUFW + k]) * q2[k];
    lgt[t] = s * SCL;
  }
  __syncthreads();
  if (t < ATTW) {
    float a = 0.f;
    for (int k = 0; k < MAXC; k++)
      a += lgt[k] * ld<F32>(P.cs1, k*ATTW + t);
    selh[t] = fmaxf(a + ld<F32>(P.bcs1, t), 0.f);
  }
  __syncthreads();
  if (t < c) {
    float a = 0.f;
    for (int k = 0; k < ATTW; k++)
      a += selh[k] * ld<F32>(P.cs2, k*MAXC + t);
    a += ld<F32>(P.bcs2, t);
    float v = 1.f / (1.f + expf(-a));
    if (F32) ((float*)P.out)[offset + t] = v;
    else     ((ushort*)P.out)[offset + t] = f2bf(v);
  }
}

__global__ void fused_v3(P27 P, const int* __restrict__ wsInt,
                         const ushort* __restrict__ wt,
                         const float* __restrict__ q2ws, int useQ2)
{
  __shared__ __align__(16) char smem[64000];
  const int t = threadIdx.x, b = blockIdx.x;
  const int f32m = wsInt[0];
  const int offset = wsInt[4 + b];
  const int c = P.counts[b];
  if (f32m) body_v3<true >(P, b, t, smem, offset, c, wt, q2ws, useQ2);
  else      body_v3<false>(P, b, t, smem, offset, c, wt, q2ws, useQ2);
}

// ================= tier-2 fallback: VERBATIM r7 (stage1-only MFMA) =================
template<bool F32>
__device__ void stage1_g(const void* X, int xb, int c,
                         const void* W, const void* Bv, ushort* hl, int t)
{
  for (int r0 = 0; r0 < MAXC; r0 += CH) {
    float acc[CH];
#pragma unroll
    for (int i = 0; i < CH; i++) acc[i] = 0.f;
    for (int k = 0; k < DIM; k++) {
      float wv = ld<F32>(W, k*HIDW + t);
#pragma unroll
      for (int i = 0; i < CH; i++) {
        int m = r0 + i;
        int mc = (m < c) ? m : 0;
        float xv = ld<F32>(X, xb + mc*DIM + k);
        acc[i] += ((m < c) ? xv : 0.f) * wv;
      }
    }
    float bb = ld<F32>(Bv, t);
#pragma unroll
    for (int i = 0; i < CH; i++)
      hl[(r0+i)*HIDW + t] = f2bf(fmaxf(acc[i] + bb, 0.f));
  }
}

template<bool F32>
__device__ void stage1_l(const ushort* S, const void* W, const void* Bv,
                         ushort* hl, int t)
{
  for (int r0 = 0; r0 < MAXC; r0 += CH) {
    float acc[CH];
#pragma unroll
    for (int i = 0; i < CH; i++) acc[i] = 0.f;
    for (int k = 0; k < ATTW; k++) {
      float wv = ld<F32>(W, k*HIDW + t);
#pragma unroll
      for (int i = 0; i < CH; i++)
        acc[i] += bf2f(S[(r0+i)*BUFW + k]) * wv;
    }
    float bb = ld<F32>(Bv, t);
#pragma unroll
    for (int i = 0; i < CH; i++)
      hl[(r0+i)*HIDW + t] = f2bf(fmaxf(acc[i] + bb, 0.f));
  }
}

template<bool F32>
__device__ void stage2(const void* W, const void* Bv, const ushort* hlp,
                       ushort* dst, int t)
{
  const int col = t & (ATTW-1);
  const int h = t >> 7;
  float bb = ld<F32>(Bv, col);
  for (int m = h; m < MAXC; m += 2) {
    float a = 0.f;
    for (int k = 0; k < HIDW; k++)
      a += bf2f(hlp[m*HIDW + k]) * ld<F32>(W, k*ATTW + col);
    dst[m*BUFW + col] = f2bf(a + bb);
  }
}

template<bool F32, bool MF>
__device__ void body(const P27& P, int b, int t,
                     ushort* hl, ushort* buf0, ushort* buf1, float* sb,
                     float* q2h, float* q2, float* logit, float* selh,
                     int offset, int c, const ushort* wt)
{
  const int xb = offset * DIM;

  if (MF) stage1_mfma<F32>(P.nodeH, xb, c, wt + O_WK1T, P.bk1, hl, HIDW, t, MAXC);
  else    stage1_g<F32>(P.nodeH, xb, c, P.wk1, P.bk1, hl, t);
  __syncthreads();
  stage2<F32>(P.wk2, P.bk2, hl, buf0, t);
  __syncthreads();
  if (MF) stage1_mfma<F32>(P.nodeH, xb, c, wt + O_WQ1T, P.bq1, hl, HIDW, t, MAXC);
  else    stage1_g<F32>(P.nodeH, xb, c, P.wq1, P.bq1, hl, t);
  __syncthreads();
  stage2<F32>(P.wq2, P.bq2, hl, buf1, t);
  __syncthreads();

  for (int idx = t; idx < MAXC*MAXC; idx += BLK) {
    int m = idx / MAXC, n = idx - m*MAXC;
    float s;
    if (m < c && n < c) {
      s = 0.f;
      for (int k = 0; k < ATTW; k++)
        s += bf2f(buf0[m*BUFW + k]) * bf2f(buf1[n*BUFW + k]);
    } else s = -1e9f;
    sb[m*SB_W + n] = s * SCL;
  }
  __syncthreads();
  if (t < MAXC) {
    float* row = sb + t*SB_W;
    float mx = row[0];
    for (int n = 1; n < MAXC; n++) mx = fmaxf(mx, row[n]);
    float sum = 0.f;
    for (int n = 0; n < MAXC; n++) { float e = expf(row[n] - mx); row[n] = e; sum += e; }
    float inv = 1.f / sum;
    for (int n = 0; n < MAXC; n++) row[n] *= inv;
  }
  __syncthreads();

  if (MF) stage1_mfma<F32>(P.nodeH, xb, c, wt + O_WV1T, P.bv1, hl, HIDW, t, MAXC);
  else    stage1_g<F32>(P.nodeH, xb, c, P.wv1, P.bv1, hl, t);
  __syncthreads();
  stage2<F32>(P.wv2, P.bv2, hl, buf0, t);
  __syncthreads();

  {
    const int col = t & (ATTW-1);
    const int h = t >> 7;
    for (int m = h; m < MAXC; m += 2) {
      float a = 0.f;
      for (int n = 0; n < MAXC; n++)
        a += sb[m*SB_W + n] * bf2f(buf0[n*BUFW + col]);
      buf1[m*BUFW + col] = f2bf(a);
    }
  }
  __syncthreads();

  stage1_l<F32>(buf1, P.uk1, P.ubk1, hl, t);
  __syncthreads();
  stage2<F32>(P.uk2, P.ubk2, hl, buf0, t);
  __syncthreads();

  {
    float a = 0.f;
    for (int k = 0; k < DIM; k++)
      a += ld<F32>(P.molA, b*DIM + k) * ld<F32>(P.uq1, k*HIDW + t);
    q2h[t] = fmaxf(a + ld<F32>(P.ubq1, t), 0.f);
  }
  __syncthreads();
  if (t < ATTW) {
    float a = 0.f;
    for (int k = 0; k < HIDW; k++)
      a += q2h[k] * ld<F32>(P.uq2, k*ATTW + t);
    q2[t] = a + ld<F32>(P.ubq2, t);
  }
  __syncthreads();
  if (t < MAXC) {
    float s = 0.f;
    for (int k = 0; k < ATTW; k++)
      s += bf2f(buf0[t*BUFW + k]) * q2[k];
    logit[t] = s * SCL;
  }
  __syncthreads();
  if (t < ATTW) {
    float a = 0.f;
    for (int k = 0; k < MAXC; k++)
      a += logit[k] * ld<F32>(P.cs1, k*ATTW + t);
    selh[t] = fmaxf(a + ld<F32>(P.bcs1, t), 0.f);
  }
  __syncthreads();
  if (t < c) {
    float a = 0.f;
    for (int k = 0; k < ATTW; k++)
      a += selh[k] * ld<F32>(P.cs2, k*MAXC + t);
    a += ld<F32>(P.bcs2, t);
    float v = 1.f / (1.f + expf(-a));
    if (F32) ((float*)P.out)[offset + t] = v;
    else     ((ushort*)P.out)[offset + t] = f2bf(v);
  }
}

__global__ void fused_mfma(P27 P, const int* __restrict__ wsInt, const ushort* __restrict__ wt)
{
  __shared__ __align__(16) ushort hl  [MAXC*HIDW];
  __shared__ __align__(16) ushort buf0[MAXC*BUFW];
  __shared__ __align__(16) ushort buf1[MAXC*BUFW];
  __shared__ __align__(16) float  sb  [MAXC*SB_W];
  __shared__ __align__(16) float  q2h [HIDW];
  __shared__ __align__(16) float  q2  [ATTW];
  __shared__ __align__(16) float  logit[64];
  __shared__ __align__(16) float  selh[ATTW];
  const int t = threadIdx.x, b = blockIdx.x;
  const int f32m = wsInt[0];
  const int offset = wsInt[4 + b];
  const int c = P.counts[b];
  if (f32m) body<true , true>(P, b, t, hl, buf0, buf1, sb, q2h, q2, logit, selh, offset, c, wt);
  else      body<false, true>(P, b, t, hl, buf0, buf1, sb, q2h, q2, logit, selh, offset, c, wt);
}

__global__ void fused_scalar(P27 P, const int* __restrict__ wsInt)
{
  __shared__ __align__(16) ushort hl  [MAXC*HIDW];
  __shared__ __align__(16) ushort buf0[MAXC*BUFW];
  __shared__ __align__(16) ushort buf1[MAXC*BUFW];
  __shared__ __align__(16) float  sb  [MAXC*SB_W];
  __shared__ __align__(16) float  q2h [HIDW];
  __shared__ __align__(16) float  q2  [ATTW];
  __shared__ __align__(16) float  logit[64];
  __shared__ __align__(16) float  selh[ATTW];
  const int t = threadIdx.x, b = blockIdx.x;
  const int f32m = wsInt[0];
  const int offset = wsInt[4 + b];
  const int c = P.counts[b];
  if (f32m) body<true , false>(P, b, t, hl, buf0, buf1, sb, q2h, q2, logit, selh, offset, c, nullptr);
  else      body<false, false>(P, b, t, hl, buf0, buf1, sb, q2h, q2, logit, selh, offset, c, nullptr);
}

extern "C" void kernel_launch(void* const* d_in, const int* in_sizes, int n_in,
                              void* d_out, int out_size, void* d_ws, size_t ws_size,
                              hipStream_t stream) {
  P27 P;
  P.molA  = d_in[0];
  P.nodeH = d_in[1];
  P.counts= (const int*)d_in[2];
  P.wq1 = d_in[3];  P.bq1 = d_in[4];  P.wq2 = d_in[5];  P.bq2 = d_in[6];
  P.wk1 = d_in[7];  P.bk1 = d_in[8];  P.wk2 = d_in[9];  P.bk2 = d_in[10];
  P.wv1 = d_in[11]; P.bv1 = d_in[12]; P.wv2 = d_in[13]; P.bv2 = d_in[14];
  P.uk1 = d_in[15]; P.ubk1= d_in[16]; P.uk2 = d_in[17]; P.ubk2= d_in[18];
  P.uq1 = d_in[19]; P.ubq1= d_in[20]; P.uq2 = d_in[21]; P.ubq2= d_in[22];
  P.cs1 = d_in[23]; P.bcs1= d_in[24]; P.cs2 = d_in[25]; P.bcs2= d_in[26];
  P.out = d_out;
  const int nb = in_sizes[2];
  int* wsInt = (int*)d_ws;

  prep_kernel<<<dim3(1), dim3(BLK), 0, stream>>>((const ushort*)d_in[0],
                                                 (const int*)d_in[2], nb, wsInt);

  const size_t need1 = (size_t)WT_BYTE_OFF + (size_t)WT_ELEMS * 2;
  const size_t need2 = (size_t)WT_BYTE_OFF + (size_t)WT_T2ELEMS * 2;
  const size_t need3 = (size_t)Q2_BYTE_OFF + (size_t)nb * ATTW * 4;

  if (ws_size >= need2) {
    ushort* wt = (ushort*)((char*)d_ws + WT_BYTE_OFF);
    unsigned long long cap = (ws_size - WT_BYTE_OFF) / 2;
    unsigned telems;
    if (ws_size >= need3)      telems = WT2_ELEMS;
    else if (ws_size >= need1) telems = WT_ELEMS;
    else                       telems = WT_T2ELEMS;
    transpose_wt<<<dim3((telems + BLK - 1)/BLK), dim3(BLK), 0, stream>>>(P, wsInt, wt, cap);

    if (ws_size >= need3) {
      float* q2ws = (float*)((char*)d_ws + Q2_BYTE_OFF);
      q2_kernel<<<dim3((nb + 63)/64), dim3(BLK), 0, stream>>>(P, wsInt, wt, q2ws, nb);
      fused_v3<<<dim3(nb), dim3(BLK), 0, stream>>>(P, wsInt, wt, q2ws, 1);
    } else if (ws_size >= need1) {
      fused_v3<<<dim3(nb), dim3(BLK), 0, stream>>>(P, wsInt, wt, nullptr, 0);
    } else {
      fused_mfma<<<dim3(nb), dim3(BLK), 0, stream>>>(P, wsInt, wt);
    }
  } else {
    fused_scalar<<<dim3(nb), dim3(BLK), 0, stream>>>(P, wsInt);
  }
}

// Round 2
// 665.616 us; speedup vs baseline: 1.3094x; 1.3094x over previous
//
#include <hip/hip_runtime.h>
#include <hip/hip_bf16.h>
#include <math.h>

#define DIM   512
#define HIDW  256
#define ATTW  128
#define MAXC  50
#define BLK   256
#define BUFW  136    // K/corr/K2 row stride (272B, 16B-aligned, 68dw = +4 banks/row)
#define QW    128    // Q row stride (256B; only 4 strided b-reads in scores -> conflicts negligible)
#define HL2   264    // hidden row stride (528B, 16B-aligned, +4 banks/row)
#define PAW   72     // pa / vt row stride (144B, 16B-aligned, +4 banks/row)
#define SB_W  52
#define CH    10
#define SCL   0.08838834764831845f  // 1/sqrt(128)

// LDS layout (52800 B total -> 3 blocks/CU, was 64000 -> 2 blocks/CU):
//   [0,26400)      hl (50x264 bf16); aliases: vt(128x72=18432), sb(50x52 f32=10400), tail scalars
//   [26400,40000)  buf0 (50x136 bf16): K, then corr, then K2-out
//   [40000,52800)  buf1 (50x128 bf16): Q; aliases pa (64x72=9216)
#define SM_BUF0 26400
#define SM_BUF1 40000
#define SM_TOTAL 52800

typedef float f32x4 __attribute__((ext_vector_type(4)));
typedef short s16x8 __attribute__((ext_vector_type(8)));

__device__ __forceinline__ float bf2f(ushort u){ union{unsigned i;float f;}v; v.i=((unsigned)u)<<16; return v.f; }
__device__ __forceinline__ ushort f2bf(float f){
  union{float f;unsigned i;}v; v.f=f;
  unsigned r = v.i + 0x7fffu + ((v.i>>16)&1u);
  return (ushort)(r>>16);
}
__device__ __forceinline__ s16x8 ldfrag(const ushort* p){ s16x8 v; __builtin_memcpy(&v, p, 16); return v; }
__device__ __forceinline__ f32x4 mfma16(s16x8 a, s16x8 b, f32x4 c){
  return __builtin_amdgcn_mfma_f32_16x16x32_bf16(a, b, c, 0, 0, 0);
}

template<bool F32>
__device__ __forceinline__ float ld(const void* p, int i){
  if (F32) return ((const float*)p)[i];
  return bf2f(((const ushort*)p)[i]);
}

struct P27 {
  const void *molA, *nodeH; const int* counts;
  const void *wq1,*bq1,*wq2,*bq2, *wk1,*bk1,*wk2,*bk2, *wv1,*bv1,*wv2,*bv2;
  const void *uk1,*ubk1,*uk2,*ubk2, *uq1,*ubq1,*uq2,*ubq2;
  const void *cs1,*bcs1,*cs2,*bcs2;
  void* out;
};

// workspace: wsInt[0]=f32flag, wsInt[4..4+nb) offsets; wt (bf16) at byte 8704
#define O_WK1T 0
#define O_WQ1T 131072
#define O_WV1T 262144
#define O_WK2T 393216
#define O_WQ2T 425984
#define O_WV2T 458752
#define O_UK1T 491520
#define O_UK2T 524288
#define WT_ELEMS   557056
#define O_UQ1TT 557056
#define O_UQ2TT 688128
#define WT2_ELEMS  720896
#define WT_T2ELEMS 393216
#define WT_BYTE_OFF 8704
#define Q2_BYTE_OFF (WT_BYTE_OFF + WT2_ELEMS*2)   // 1450496, 16B-aligned

// ---------- prep: dtype detect + exclusive scan (VERBATIM, validated) ----------
__global__ void prep_kernel(const ushort* __restrict__ molAu,
                            const int* __restrict__ counts, int nb,
                            int* __restrict__ wsInt)
{
  __shared__ int part[BLK];
  __shared__ int cnt;
  const int t = threadIdx.x;
  if (t == 0) cnt = 0;
  __syncthreads();
  int e = (molAu[t] >> 7) & 0xFF;
  if (e >= 100 && e <= 140) atomicAdd(&cnt, 1);
  const int per = (nb + BLK - 1) / BLK;
  int s = 0;
  for (int i = 0; i < per; i++) { int idx = t*per + i; if (idx < nb) s += counts[idx]; }
  part[t] = s;
  __syncthreads();
  if (t == 0) {
    int run = 0;
    for (int i = 0; i < BLK; i++) { int v = part[i]; part[i] = run; run += v; }
    wsInt[0] = (cnt >= 220) ? 0 : 1;        // 0 = bf16 inputs, 1 = f32 inputs
  }
  __syncthreads();
  int run = part[t];
  for (int i = 0; i < per; i++) {
    int idx = t*per + i;
    if (idx < nb) { wsInt[4 + idx] = run; run += counts[idx]; }
  }
}

// ---------- prep: transpose+convert weight matrices -> bf16 (bounds-guarded) ----------
__global__ void transpose_wt(P27 P, const int* __restrict__ wsInt,
                             ushort* __restrict__ wt, unsigned long long cap_elems)
{
  unsigned i = blockIdx.x*BLK + threadIdx.x;
  if (i >= WT2_ELEMS) return;
  if ((unsigned long long)i >= cap_elems) return;
  const int f32m = wsInt[0];
  const void* src; int idx;
  if (i < O_WK2T) {                 // w1: (512x256) -> (256x512)
    int m = i / 131072; int j = i - m*131072;
    src = (m==0) ? P.wk1 : ((m==1) ? P.wq1 : P.wv1);
    int n = j >> 9, k = j & 511;
    idx = k*HIDW + n;
  } else if (i < O_UK1T) {          // w2: (256x128) -> (128x256)
    int m = (i - O_WK2T) / 32768; int j = (i - O_WK2T) - m*32768;
    src = (m==0) ? P.wk2 : ((m==1) ? P.wq2 : P.wv2);
    int n = j >> 8, k = j & 255;
    idx = k*ATTW + n;
  } else if (i < O_UK2T) {          // uk1: (128x256) -> (256x128)
    int j = i - O_UK1T; src = P.uk1;
    int n = j >> 7, k = j & 127;
    idx = k*HIDW + n;
  } else if (i < O_UQ1TT) {         // uk2: (256x128) -> (128x256)
    int j = i - O_UK2T; src = P.uk2;
    int n = j >> 8, k = j & 255;
    idx = k*ATTW + n;
  } else if (i < O_UQ2TT) {         // uq1: (512x256) -> (256x512)
    int j = i - O_UQ1TT; src = P.uq1;
    int n = j >> 9, k = j & 511;
    idx = k*HIDW + n;
  } else {                          // uq2: (256x128) -> (128x256)
    int j = i - O_UQ2TT; src = P.uq2;
    int n = j >> 8, k = j & 255;
    idx = k*ATTW + n;
  }
  float v = f32m ? ((const float*)src)[idx] : bf2f(((const ushort*)src)[idx]);
  wt[i] = f2bf(v);
}

// ---------- prep: convert nodeH -> bf16 copy (halves X traffic & A-frag loads) ----------
__global__ void xconv_kernel(const void* __restrict__ X, const int* __restrict__ wsInt,
                             ushort* __restrict__ xbf, long nelem)
{
  long i = ((long)blockIdx.x*BLK + threadIdx.x)*8;
  if (i >= nelem) return;
  if (wsInt[0]) {
    const float* p = (const float*)X + i;
    f32x4 v0, v1; __builtin_memcpy(&v0, p, 16); __builtin_memcpy(&v1, p+4, 16);
    s16x8 o;
#pragma unroll
    for (int j = 0; j < 4; j++) { o[j] = (short)f2bf(v0[j]); o[4+j] = (short)f2bf(v1[j]); }
    __builtin_memcpy(xbf + i, &o, 16);
  } else {
    s16x8 o; __builtin_memcpy(&o, (const ushort*)X + i, 16);
    __builtin_memcpy(xbf + i, &o, 16);
  }
}

// ---------- MFMA stage1: X rows (pads=0) @ W1t(256x512) + b1, relu -> hl ----------
// XB=true: X is pre-converted bf16 (xbf). Else F32 selects cvt vs raw-bf16 path.
template<bool F32, bool XB>
__device__ __forceinline__ void stage1_mfma(const void* __restrict__ X, int xb, int c,
                                            const ushort* __restrict__ Wt,
                                            const void* __restrict__ Bv,
                                            ushort* __restrict__ hl, int hls, int t,
                                            int wlim)
{
  const int w = t >> 6, L = t & 63, quad = L >> 4, l16 = L & 15;
  f32x4 acc[4][4];
#pragma unroll
  for (int i = 0; i < 4; i++)
#pragma unroll
    for (int j = 0; j < 4; j++) acc[i][j] = (f32x4){0.f,0.f,0.f,0.f};

  bool va[4]; int rr[4];
#pragma unroll
  for (int mt = 0; mt < 4; mt++) {
    int row = mt*16 + l16;
    va[mt] = (row < c);
    rr[mt] = va[mt] ? row : 0;
  }
  const ushort* pB = Wt + (size_t)(w*64 + l16)*DIM + quad*8;

#pragma unroll 2
  for (int k0 = 0; k0 < DIM; k0 += 32) {
    s16x8 a[4];
#pragma unroll
    for (int mt = 0; mt < 4; mt++) {
      s16x8 z = {};
      if (va[mt]) {
        if (XB || !F32) {
          a[mt] = ldfrag((const ushort*)X + xb + rr[mt]*DIM + k0 + quad*8);
        } else {
          const float* xp = (const float*)X + xb + rr[mt]*DIM + k0 + quad*8;
          f32x4 v0, v1;
          __builtin_memcpy(&v0, xp, 16);
          __builtin_memcpy(&v1, xp+4, 16);
          s16x8 v;
#pragma unroll
          for (int j = 0; j < 4; j++) { v[j] = (short)f2bf(v0[j]); v[4+j] = (short)f2bf(v1[j]); }
          a[mt] = v;
        }
      } else a[mt] = z;
    }
#pragma unroll
    for (int nt = 0; nt < 4; nt++) {
      s16x8 b = ldfrag(pB + (size_t)nt*16*DIM + k0);
#pragma unroll
      for (int mt = 0; mt < 4; mt++)
        acc[mt][nt] = mfma16(a[mt], b, acc[mt][nt]);
    }
  }
#pragma unroll
  for (int nt = 0; nt < 4; nt++) {
    int col = w*64 + nt*16 + l16;
    float bb = ld<F32>(Bv, col);
#pragma unroll
    for (int mt = 0; mt < 4; mt++)
#pragma unroll
      for (int r = 0; r < 4; r++) {
        int row = mt*16 + quad*4 + r;
        if (row < wlim)
          hl[row*hls + col] = f2bf(fmaxf(acc[mt][nt][r] + bb, 0.f));
      }
  }
}

// ---------- MFMA stage2: hl(50 x HL2) @ W2t(128x256) + b2 -> dst(50 x ds) ----------
template<bool F32>
__device__ __forceinline__ void stage2_mfma(const ushort* __restrict__ hl,
                                            const ushort* __restrict__ W2t,
                                            const void* __restrict__ Bv,
                                            ushort* __restrict__ dst, int ds, int t)
{
  const int w = t >> 6, L = t & 63, quad = L >> 4, l16 = L & 15;
  f32x4 acc[4][2];
#pragma unroll
  for (int i = 0; i < 4; i++) { acc[i][0] = (f32x4){0.f,0.f,0.f,0.f}; acc[i][1] = (f32x4){0.f,0.f,0.f,0.f}; }
  const ushort* pB = W2t + (size_t)(w*32 + l16)*HIDW + quad*8;
#pragma unroll 2
  for (int k0 = 0; k0 < HIDW; k0 += 32) {
    s16x8 b0 = ldfrag(pB + k0);
    s16x8 b1 = ldfrag(pB + (size_t)16*HIDW + k0);
#pragma unroll
    for (int mt = 0; mt < 4; mt++) {
      s16x8 a = ldfrag(hl + (mt*16 + l16)*HL2 + k0 + quad*8);  // rows>=50 junk, discarded (in-bounds of smem)
      acc[mt][0] = mfma16(a, b0, acc[mt][0]);
      acc[mt][1] = mfma16(a, b1, acc[mt][1]);
    }
  }
#pragma unroll
  for (int nt = 0; nt < 2; nt++) {
    int col = w*32 + nt*16 + l16;
    float bb = ld<F32>(Bv, col);
#pragma unroll
    for (int mt = 0; mt < 4; mt++)
#pragma unroll
      for (int r = 0; r < 4; r++) {
        int row = mt*16 + quad*4 + r;
        if (row < MAXC)
          dst[row*ds + col] = f2bf(acc[mt][nt][r] + bb);
      }
  }
}

// ---------- MFMA stage2-V: hl @ W2t + b2 -> vt TRANSPOSED (vt aliases hl!) ----------
template<bool F32>
__device__ __forceinline__ void stage2v_vt(const ushort* __restrict__ hl,
                                           const ushort* __restrict__ W2t,
                                           const void* __restrict__ Bv,
                                           ushort* __restrict__ vt, int t)
{
  const int w = t >> 6, L = t & 63, quad = L >> 4, l16 = L & 15;
  f32x4 acc[4][2];
#pragma unroll
  for (int i = 0; i < 4; i++) { acc[i][0] = (f32x4){0.f,0.f,0.f,0.f}; acc[i][1] = (f32x4){0.f,0.f,0.f,0.f}; }
  const ushort* pB = W2t + (size_t)(w*32 + l16)*HIDW + quad*8;
  for (int k0 = 0; k0 < HIDW; k0 += 32) {
    s16x8 b0 = ldfrag(pB + k0);
    s16x8 b1 = ldfrag(pB + (size_t)16*HIDW + k0);
#pragma unroll
    for (int mt = 0; mt < 4; mt++) {
      s16x8 a = ldfrag(hl + (mt*16 + l16)*HL2 + k0 + quad*8);
      acc[mt][0] = mfma16(a, b0, acc[mt][0]);
      acc[mt][1] = mfma16(a, b1, acc[mt][1]);
    }
  }
  __syncthreads();   // all hl reads complete before overwriting (vt aliases hl region)
#pragma unroll
  for (int nt = 0; nt < 2; nt++) {
    int col = w*32 + nt*16 + l16;
    float bb = ld<F32>(Bv, col);
#pragma unroll
    for (int mt = 0; mt < 4; mt++)
#pragma unroll
      for (int r = 0; r < 4; r++) {
        int row = mt*16 + quad*4 + r;
        if (row < MAXC)
          vt[col*PAW + row] = f2bf(acc[mt][nt][r] + bb);
      }
  }
  // zero k-dim pad rows [50,64) for every col (junk here would poison corr via NaN)
  for (int idx = t; idx < ATTW*(64-MAXC); idx += BLK) {
    int cc = idx / (64-MAXC), rr2 = MAXC + idx % (64-MAXC);
    vt[cc*PAW + rr2] = 0;
  }
}

// ---------- MFMA K2-stage1: src(50 x BUFW) @ W1t(256x128) + b, relu -> hl ----------
template<bool F32>
__device__ __forceinline__ void s1l_mfma(const ushort* __restrict__ src,
                                         const ushort* __restrict__ W1t,
                                         const void* __restrict__ Bv,
                                         ushort* __restrict__ hl, int t)
{
  const int w = t >> 6, L = t & 63, quad = L >> 4, l16 = L & 15;
  f32x4 acc[4][4];
#pragma unroll
  for (int i = 0; i < 4; i++)
#pragma unroll
    for (int j = 0; j < 4; j++) acc[i][j] = (f32x4){0.f,0.f,0.f,0.f};
  const ushort* pB = W1t + (size_t)(w*64 + l16)*ATTW + quad*8;
  for (int k0 = 0; k0 < ATTW; k0 += 32) {
    s16x8 b[4];
#pragma unroll
    for (int nt = 0; nt < 4; nt++) b[nt] = ldfrag(pB + (size_t)nt*16*ATTW + k0);
#pragma unroll
    for (int mt = 0; mt < 4; mt++) {
      s16x8 a = ldfrag(src + (mt*16 + l16)*BUFW + k0 + quad*8);  // rows>=50 junk, discarded
#pragma unroll
      for (int nt = 0; nt < 4; nt++)
        acc[mt][nt] = mfma16(a, b[nt], acc[mt][nt]);
    }
  }
#pragma unroll
  for (int nt = 0; nt < 4; nt++) {
    int col = w*64 + nt*16 + l16;
    float bb = ld<F32>(Bv, col);
#pragma unroll
    for (int mt = 0; mt < 4; mt++)
#pragma unroll
      for (int r = 0; r < 4; r++) {
        int row = mt*16 + quad*4 + r;
        if (row < MAXC)
          hl[row*HL2 + col] = f2bf(fmaxf(acc[mt][nt][r] + bb, 0.f));
      }
  }
}

// ---------- MFMA scores: K(buf0) @ Q(buf1)^T -> sb (masked, scaled) ----------
__device__ __forceinline__ void scores_mfma(const ushort* __restrict__ buf0,
                                            const ushort* __restrict__ buf1,
                                            float* __restrict__ sb, int c, int t)
{
  const int w = t >> 6, L = t & 63, quad = L >> 4, l16 = L & 15;
  f32x4 acc[4];
#pragma unroll
  for (int i = 0; i < 4; i++) acc[i] = (f32x4){0.f,0.f,0.f,0.f};
  const int col = w*16 + l16;
  const int cb = (col < MAXC) ? col : 0;            // clamp junk cols (stay in 50-row buf1)
  const ushort* pB = buf1 + cb*QW + quad*8;
  for (int k0 = 0; k0 < ATTW; k0 += 32) {
    s16x8 b = ldfrag(pB + k0);
#pragma unroll
    for (int mt = 0; mt < 4; mt++) {
      s16x8 a = ldfrag(buf0 + (mt*16 + l16)*BUFW + k0 + quad*8);
      acc[mt] = mfma16(a, b, acc[mt]);
    }
  }
#pragma unroll
  for (int mt = 0; mt < 4; mt++)
#pragma unroll
    for (int r = 0; r < 4; r++) {
      int row = mt*16 + quad*4 + r;
      if (row < MAXC && col < MAXC)
        sb[row*SB_W + col] = (row < c && col < c) ? acc[mt][r]*SCL : -1e9f*SCL;
    }
}

// ---------- parallel softmax (4 lanes/row) + P->bf16 into pa ----------
__device__ __forceinline__ void softmax_pa(float* __restrict__ sb,
                                           ushort* __restrict__ pa, int c, int t)
{
  const int m = t >> 2, j = t & 3;
  if (m < MAXC) {
    float* row = sb + m*SB_W;
    float mx = -3.4e38f;
    for (int n = j; n < MAXC; n += 4) mx = fmaxf(mx, row[n]);
    mx = fmaxf(mx, __shfl_xor(mx, 1));
    mx = fmaxf(mx, __shfl_xor(mx, 2));
    float sum = 0.f;
    for (int n = j; n < MAXC; n += 4) { float e = expf(row[n] - mx); row[n] = e; sum += e; }
    sum += __shfl_xor(sum, 1);
    sum += __shfl_xor(sum, 2);
    float inv = 1.f / sum;
    for (int n = j; n < 64; n += 4)
      pa[m*PAW + n] = (n < MAXC) ? f2bf(row[n] * inv) : (ushort)0;
  }
}

// ---------- MFMA corr: pa(P bf16) @ vt(V^T) -> dst(50 x BUFW) ----------
__device__ __forceinline__ void corr_mfma(const ushort* __restrict__ pa,
                                          const ushort* __restrict__ vt,
                                          ushort* __restrict__ dst, int t)
{
  const int w = t >> 6, L = t & 63, quad = L >> 4, l16 = L & 15;
  f32x4 acc[4][2];
#pragma unroll
  for (int i = 0; i < 4; i++) { acc[i][0] = (f32x4){0.f,0.f,0.f,0.f}; acc[i][1] = (f32x4){0.f,0.f,0.f,0.f}; }
  const ushort* pB = vt + (size_t)(w*32 + l16)*PAW + quad*8;
  for (int k0 = 0; k0 < 64; k0 += 32) {
    s16x8 b0 = ldfrag(pB + k0);
    s16x8 b1 = ldfrag(pB + (size_t)16*PAW + k0);
#pragma unroll
    for (int mt = 0; mt < 4; mt++) {
      s16x8 a = ldfrag(pa + (mt*16 + l16)*PAW + k0 + quad*8);   // rows>=50 junk, discarded
      acc[mt][0] = mfma16(a, b0, acc[mt][0]);
      acc[mt][1] = mfma16(a, b1, acc[mt][1]);
    }
  }
#pragma unroll
  for (int nt = 0; nt < 2; nt++) {
    int col = w*32 + nt*16 + l16;
#pragma unroll
    for (int mt = 0; mt < 4; mt++)
#pragma unroll
      for (int r = 0; r < 4; r++) {
        int row = mt*16 + quad*4 + r;
        if (row < MAXC)
          dst[row*BUFW + col] = f2bf(acc[mt][nt][r]);
      }
  }
}

// ---------- Q2 pre-kernel: molA @ uq1t relu @ uq2t -> q2ws (one-shot GEMM) ----------
template<bool F32>
__device__ void q2_body(const P27& P, const ushort* __restrict__ wt,
                        float* __restrict__ q2ws, int b0, int rows, int t,
                        ushort* __restrict__ hq)
{
  stage1_mfma<F32,false>(P.molA, b0*DIM, rows, wt + O_UQ1TT, P.ubq1, hq, HL2, t, 64);
  __syncthreads();
  const int w = t >> 6, L = t & 63, quad = L >> 4, l16 = L & 15;
  f32x4 acc[4][2];
#pragma unroll
  for (int i = 0; i < 4; i++) { acc[i][0] = (f32x4){0.f,0.f,0.f,0.f}; acc[i][1] = (f32x4){0.f,0.f,0.f,0.f}; }
  const ushort* pB = wt + O_UQ2TT + (size_t)(w*32 + l16)*HIDW + quad*8;
  for (int k0 = 0; k0 < HIDW; k0 += 32) {
    s16x8 bf0 = ldfrag(pB + k0);
    s16x8 bf1 = ldfrag(pB + (size_t)16*HIDW + k0);
#pragma unroll
    for (int mt = 0; mt < 4; mt++) {
      s16x8 a = ldfrag(hq + (mt*16 + l16)*HL2 + k0 + quad*8);
      acc[mt][0] = mfma16(a, bf0, acc[mt][0]);
      acc[mt][1] = mfma16(a, bf1, acc[mt][1]);
    }
  }
#pragma unroll
  for (int nt = 0; nt < 2; nt++) {
    int col = w*32 + nt*16 + l16;
    float bb = ld<F32>(P.ubq2, col);
#pragma unroll
    for (int mt = 0; mt < 4; mt++)
#pragma unroll
      for (int r = 0; r < 4; r++) {
        int row = mt*16 + quad*4 + r;
        if (row < rows)
          q2ws[(size_t)(b0 + row)*ATTW + col] = acc[mt][nt][r] + bb;
      }
  }
}

__global__ void q2_kernel(P27 P, const int* __restrict__ wsInt,
                          const ushort* __restrict__ wt, float* __restrict__ q2ws, int nb)
{
  __shared__ __align__(16) ushort hq[64*HL2];
  const int t = threadIdx.x;
  const int b0 = blockIdx.x*64;
  int rows = nb - b0; if (rows > 64) rows = 64;
  if (rows <= 0) return;
  if (wsInt[0]) q2_body<true >(P, wt, q2ws, b0, rows, t, hq);
  else          q2_body<false>(P, wt, q2ws, b0, rows, t, hq);
}

// ================= tier-0/1 body: MFMA everywhere, 3 blocks/CU =================
template<bool F32, bool XB>
__device__ void body_v3(const P27& P, int b, int t, char* smem,
                        int offset, int c, const ushort* __restrict__ wt,
                        const float* __restrict__ q2ws, const ushort* __restrict__ xbf,
                        int useQ2)
{
  ushort* hl   = (ushort*)smem;                 // 26400 B
  ushort* vt   = (ushort*)smem;                 // alias (18432)
  float*  sb   = (float*)smem;                  // alias (10400) - hl(Q) dead at scores
  ushort* buf0 = (ushort*)(smem + SM_BUF0);     // 13600, stride 136
  ushort* buf1 = (ushort*)(smem + SM_BUF1);     // 12800, stride 128
  ushort* pa   = buf1;                          // alias (9216, stride 72)
  float* q2h  = (float*)smem;                   // tail scalars alias hl (dead)
  float* q2   = (float*)(smem + 1024);
  float* lgt  = (float*)(smem + 1536);
  float* selh = (float*)(smem + 1792);

  const int xb = offset * DIM;
  const void* Xs = XB ? (const void*)xbf : P.nodeH;

  // K -> buf0
  stage1_mfma<F32,XB>(Xs, xb, c, wt + O_WK1T, P.bk1, hl, HL2, t, MAXC);
  __syncthreads();
  stage2_mfma<F32>(hl, wt + O_WK2T, P.bk2, buf0, BUFW, t);
  __syncthreads();
  // Q -> buf1 (stride 128)
  stage1_mfma<F32,XB>(Xs, xb, c, wt + O_WQ1T, P.bq1, hl, HL2, t, MAXC);
  __syncthreads();
  stage2_mfma<F32>(hl, wt + O_WQ2T, P.bq2, buf1, QW, t);
  __syncthreads();

  // scores via MFMA -> sb (aliases hl; Q-hidden dead)
  scores_mfma(buf0, buf1, sb, c, t);
  __syncthreads();
  // softmax (4 lanes/row) + P->bf16 into pa (overwrites buf1=Q, dead)
  softmax_pa(sb, pa, c, t);
  __syncthreads();

  // V -> vt (transposed; vt aliases hl/sb, internal barrier inside)
  stage1_mfma<F32,XB>(Xs, xb, c, wt + O_WV1T, P.bv1, hl, HL2, t, MAXC);
  __syncthreads();
  stage2v_vt<F32>(hl, wt + O_WV2T, P.bv2, vt, t);
  __syncthreads();

  // corr = P @ V via MFMA -> buf0 (K dead)
  corr_mfma(pa, vt, buf0, t);
  __syncthreads();

  // K2 (both stages MFMA): corr(buf0) -> hl -> buf0 (corr dead)
  s1l_mfma<F32>(buf0, wt + O_UK1T, P.ubk1, hl, t);
  __syncthreads();
  stage2_mfma<F32>(hl, wt + O_UK2T, P.ubk2, buf0, BUFW, t);
  __syncthreads();

  // Q2: hoisted (read precomputed) or inline fallback
  if (useQ2) {
    if (t < ATTW) q2[t] = q2ws[(size_t)b*ATTW + t];
  } else {
    float a = 0.f;
    for (int k = 0; k < DIM; k++)
      a += ld<F32>(P.molA, b*DIM + k) * ld<F32>(P.uq1, k*HIDW + t);
    q2h[t] = fmaxf(a + ld<F32>(P.ubq1, t), 0.f);
    __syncthreads();
    if (t < ATTW) {
      float a2 = 0.f;
      for (int k = 0; k < HIDW; k++)
        a2 += q2h[k] * ld<F32>(P.uq2, k*ATTW + t);
      q2[t] = a2 + ld<F32>(P.ubq2, t);
    }
  }
  __syncthreads();
  if (t < MAXC) {
    float s = 0.f;
    for (int k = 0; k < ATTW; k++)
      s += bf2f(buf0[t*BUFW + k]) * q2[k];
    lgt[t] = s * SCL;
  }
  __syncthreads();
  if (t < ATTW) {
    float a = 0.f;
    for (int k = 0; k < MAXC; k++)
      a += lgt[k] * ld<F32>(P.cs1, k*ATTW + t);
    selh[t] = fmaxf(a + ld<F32>(P.bcs1, t), 0.f);
  }
  __syncthreads();
  if (t < c) {
    float a = 0.f;
    for (int k = 0; k < ATTW; k++)
      a += selh[k] * ld<F32>(P.cs2, k*MAXC + t);
    a += ld<F32>(P.bcs2, t);
    float v = 1.f / (1.f + expf(-a));
    if (F32) ((float*)P.out)[offset + t] = v;
    else     ((ushort*)P.out)[offset + t] = f2bf(v);
  }
}

__global__ void __launch_bounds__(BLK, 3)
fused_v3(P27 P, const int* __restrict__ wsInt,
         const ushort* __restrict__ wt,
         const float* __restrict__ q2ws, const ushort* __restrict__ xbf, int useQ2)
{
  __shared__ __align__(16) char smem[SM_TOTAL];
  const int t = threadIdx.x, b = blockIdx.x;
  const int f32m = wsInt[0];
  const int offset = wsInt[4 + b];
  const int c = P.counts[b];
  if (f32m) {
    if (xbf) body_v3<true , true >(P, b, t, smem, offset, c, wt, q2ws, xbf, useQ2);
    else     body_v3<true , false>(P, b, t, smem, offset, c, wt, q2ws, xbf, useQ2);
  } else {
    if (xbf) body_v3<false, true >(P, b, t, smem, offset, c, wt, q2ws, xbf, useQ2);
    else     body_v3<false, false>(P, b, t, smem, offset, c, wt, q2ws, xbf, useQ2);
  }
}

// ================= tier-2 fallback: VERBATIM r7 (stage1-only MFMA) =================
template<bool F32>
__device__ void stage1_g(const void* X, int xb, int c,
                         const void* W, const void* Bv, ushort* hl, int t)
{
  for (int r0 = 0; r0 < MAXC; r0 += CH) {
    float acc[CH];
#pragma unroll
    for (int i = 0; i < CH; i++) acc[i] = 0.f;
    for (int k = 0; k < DIM; k++) {
      float wv = ld<F32>(W, k*HIDW + t);
#pragma unroll
      for (int i = 0; i < CH; i++) {
        int m = r0 + i;
        int mc = (m < c) ? m : 0;
        float xv = ld<F32>(X, xb + mc*DIM + k);
        acc[i] += ((m < c) ? xv : 0.f) * wv;
      }
    }
    float bb = ld<F32>(Bv, t);
#pragma unroll
    for (int i = 0; i < CH; i++)
      hl[(r0+i)*HIDW + t] = f2bf(fmaxf(acc[i] + bb, 0.f));
  }
}

template<bool F32>
__device__ void stage1_l(const ushort* S, const void* W, const void* Bv,
                         ushort* hl, int t)
{
  for (int r0 = 0; r0 < MAXC; r0 += CH) {
    float acc[CH];
#pragma unroll
    for (int i = 0; i < CH; i++) acc[i] = 0.f;
    for (int k = 0; k < ATTW; k++) {
      float wv = ld<F32>(W, k*HIDW + t);
#pragma unroll
      for (int i = 0; i < CH; i++)
        acc[i] += bf2f(S[(r0+i)*BUFW + k]) * wv;
    }
    float bb = ld<F32>(Bv, t);
#pragma unroll
    for (int i = 0; i < CH; i++)
      hl[(r0+i)*HIDW + t] = f2bf(fmaxf(acc[i] + bb, 0.f));
  }
}

template<bool F32>
__device__ void stage2(const void* W, const void* Bv, const ushort* hlp,
                       ushort* dst, int t)
{
  const int col = t & (ATTW-1);
  const int h = t >> 7;
  float bb = ld<F32>(Bv, col);
  for (int m = h; m < MAXC; m += 2) {
    float a = 0.f;
    for (int k = 0; k < HIDW; k++)
      a += bf2f(hlp[m*HIDW + k]) * ld<F32>(W, k*ATTW + col);
    dst[m*BUFW + col] = f2bf(a + bb);
  }
}

template<bool F32, bool MF>
__device__ void body(const P27& P, int b, int t,
                     ushort* hl, ushort* buf0, ushort* buf1, float* sb,
                     float* q2h, float* q2, float* logit, float* selh,
                     int offset, int c, const ushort* wt)
{
  const int xb = offset * DIM;

  if (MF) stage1_mfma<F32,false>(P.nodeH, xb, c, wt + O_WK1T, P.bk1, hl, HIDW, t, MAXC);
  else    stage1_g<F32>(P.nodeH, xb, c, P.wk1, P.bk1, hl, t);
  __syncthreads();
  stage2<F32>(P.wk2, P.bk2, hl, buf0, t);
  __syncthreads();
  if (MF) stage1_mfma<F32,false>(P.nodeH, xb, c, wt + O_WQ1T, P.bq1, hl, HIDW, t, MAXC);
  else    stage1_g<F32>(P.nodeH, xb, c, P.wq1, P.bq1, hl, t);
  __syncthreads();
  stage2<F32>(P.wq2, P.bq2, hl, buf1, t);
  __syncthreads();

  for (int idx = t; idx < MAXC*MAXC; idx += BLK) {
    int m = idx / MAXC, n = idx - m*MAXC;
    float s;
    if (m < c && n < c) {
      s = 0.f;
      for (int k = 0; k < ATTW; k++)
        s += bf2f(buf0[m*BUFW + k]) * bf2f(buf1[n*BUFW + k]);
    } else s = -1e9f;
    sb[m*SB_W + n] = s * SCL;
  }
  __syncthreads();
  if (t < MAXC) {
    float* row = sb + t*SB_W;
    float mx = row[0];
    for (int n = 1; n < MAXC; n++) mx = fmaxf(mx, row[n]);
    float sum = 0.f;
    for (int n = 0; n < MAXC; n++) { float e = expf(row[n] - mx); row[n] = e; sum += e; }
    float inv = 1.f / sum;
    for (int n = 0; n < MAXC; n++) row[n] *= inv;
  }
  __syncthreads();

  if (MF) stage1_mfma<F32,false>(P.nodeH, xb, c, wt + O_WV1T, P.bv1, hl, HIDW, t, MAXC);
  else    stage1_g<F32>(P.nodeH, xb, c, P.wv1, P.bv1, hl, t);
  __syncthreads();
  stage2<F32>(P.wv2, P.bv2, hl, buf0, t);
  __syncthreads();

  {
    const int col = t & (ATTW-1);
    const int h = t >> 7;
    for (int m = h; m < MAXC; m += 2) {
      float a = 0.f;
      for (int n = 0; n < MAXC; n++)
        a += sb[m*SB_W + n] * bf2f(buf0[n*BUFW + col]);
      buf1[m*BUFW + col] = f2bf(a);
    }
  }
  __syncthreads();

  stage1_l<F32>(buf1, P.uk1, P.ubk1, hl, t);
  __syncthreads();
  stage2<F32>(P.uk2, P.ubk2, hl, buf0, t);
  __syncthreads();

  {
    float a = 0.f;
    for (int k = 0; k < DIM; k++)
      a += ld<F32>(P.molA, b*DIM + k) * ld<F32>(P.uq1, k*HIDW + t);
    q2h[t] = fmaxf(a + ld<F32>(P.ubq1, t), 0.f);
  }
  __syncthreads();
  if (t < ATTW) {
    float a = 0.f;
    for (int k = 0; k < HIDW; k++)
      a += q2h[k] * ld<F32>(P.uq2, k*ATTW + t);
    q2[t] = a + ld<F32>(P.ubq2, t);
  }
  __syncthreads();
  if (t < MAXC) {
    float s = 0.f;
    for (int k = 0; k < ATTW; k++)
      s += bf2f(buf0[t*BUFW + k]) * q2[k];
    logit[t] = s * SCL;
  }
  __syncthreads();
  if (t < ATTW) {
    float a = 0.f;
    for (int k = 0; k < MAXC; k++)
      a += logit[k] * ld<F32>(P.cs1, k*ATTW + t);
    selh[t] = fmaxf(a + ld<F32>(P.bcs1, t), 0.f);
  }
  __syncthreads();
  if (t < c) {
    float a = 0.f;
    for (int k = 0; k < ATTW; k++)
      a += selh[k] * ld<F32>(P.cs2, k*MAXC + t);
    a += ld<F32>(P.bcs2, t);
    float v = 1.f / (1.f + expf(-a));
    if (F32) ((float*)P.out)[offset + t] = v;
    else     ((ushort*)P.out)[offset + t] = f2bf(v);
  }
}

__global__ void fused_mfma(P27 P, const int* __restrict__ wsInt, const ushort* __restrict__ wt)
{
  __shared__ __align__(16) ushort hl  [MAXC*HIDW];
  __shared__ __align__(16) ushort buf0[MAXC*BUFW];
  __shared__ __align__(16) ushort buf1[MAXC*BUFW];
  __shared__ __align__(16) float  sb  [MAXC*SB_W];
  __shared__ __align__(16) float  q2h [HIDW];
  __shared__ __align__(16) float  q2  [ATTW];
  __shared__ __align__(16) float  logit[64];
  __shared__ __align__(16) float  selh[ATTW];
  const int t = threadIdx.x, b = blockIdx.x;
  const int f32m = wsInt[0];
  const int offset = wsInt[4 + b];
  const int c = P.counts[b];
  if (f32m) body<true , true>(P, b, t, hl, buf0, buf1, sb, q2h, q2, logit, selh, offset, c, wt);
  else      body<false, true>(P, b, t, hl, buf0, buf1, sb, q2h, q2, logit, selh, offset, c, wt);
}

__global__ void fused_scalar(P27 P, const int* __restrict__ wsInt)
{
  __shared__ __align__(16) ushort hl  [MAXC*HIDW];
  __shared__ __align__(16) ushort buf0[MAXC*BUFW];
  __shared__ __align__(16) ushort buf1[MAXC*BUFW];
  __shared__ __align__(16) float  sb  [MAXC*SB_W];
  __shared__ __align__(16) float  q2h [HIDW];
  __shared__ __align__(16) float  q2  [ATTW];
  __shared__ __align__(16) float  logit[64];
  __shared__ __align__(16) float  selh[ATTW];
  const int t = threadIdx.x, b = blockIdx.x;
  const int f32m = wsInt[0];
  const int offset = wsInt[4 + b];
  const int c = P.counts[b];
  if (f32m) body<true , false>(P, b, t, hl, buf0, buf1, sb, q2h, q2, logit, selh, offset, c, nullptr);
  else      body<false, false>(P, b, t, hl, buf0, buf1, sb, q2h, q2, logit, selh, offset, c, nullptr);
}

extern "C" void kernel_launch(void* const* d_in, const int* in_sizes, int n_in,
                              void* d_out, int out_size, void* d_ws, size_t ws_size,
                              hipStream_t stream) {
  P27 P;
  P.molA  = d_in[0];
  P.nodeH = d_in[1];
  P.counts= (const int*)d_in[2];
  P.wq1 = d_in[3];  P.bq1 = d_in[4];  P.wq2 = d_in[5];  P.bq2 = d_in[6];
  P.wk1 = d_in[7];  P.bk1 = d_in[8];  P.wk2 = d_in[9];  P.bk2 = d_in[10];
  P.wv1 = d_in[11]; P.bv1 = d_in[12]; P.wv2 = d_in[13]; P.bv2 = d_in[14];
  P.uk1 = d_in[15]; P.ubk1= d_in[16]; P.uk2 = d_in[17]; P.ubk2= d_in[18];
  P.uq1 = d_in[19]; P.ubq1= d_in[20]; P.uq2 = d_in[21]; P.ubq2= d_in[22];
  P.cs1 = d_in[23]; P.bcs1= d_in[24]; P.cs2 = d_in[25]; P.bcs2= d_in[26];
  P.out = d_out;
  const int nb = in_sizes[2];
  int* wsInt = (int*)d_ws;

  prep_kernel<<<dim3(1), dim3(BLK), 0, stream>>>((const ushort*)d_in[0],
                                                 (const int*)d_in[2], nb, wsInt);

  const size_t need1 = (size_t)WT_BYTE_OFF + (size_t)WT_ELEMS * 2;
  const size_t need2 = (size_t)WT_BYTE_OFF + (size_t)WT_T2ELEMS * 2;
  const size_t need3 = (size_t)Q2_BYTE_OFF + (size_t)nb * ATTW * 4;
  size_t xbf_off = ((size_t)Q2_BYTE_OFF + (size_t)nb * ATTW * 4 + 255) & ~(size_t)255;
  const size_t xelems = (size_t)in_sizes[1];           // nodeH element count (N*512)
  const size_t need4 = xbf_off + xelems * 2;

  if (ws_size >= need2) {
    ushort* wt = (ushort*)((char*)d_ws + WT_BYTE_OFF);
    unsigned long long cap = (ws_size - WT_BYTE_OFF) / 2;
    unsigned telems;
    if (ws_size >= need3)      telems = WT2_ELEMS;
    else if (ws_size >= need1) telems = WT_ELEMS;
    else                       telems = WT_T2ELEMS;
    transpose_wt<<<dim3((telems + BLK - 1)/BLK), dim3(BLK), 0, stream>>>(P, wsInt, wt, cap);

    if (ws_size >= need3) {
      float* q2ws = (float*)((char*)d_ws + Q2_BYTE_OFF);
      ushort* xbf = nullptr;
      if (ws_size >= need4) {
        xbf = (ushort*)((char*)d_ws + xbf_off);
        long n8 = (long)((xelems + 7) / 8);
        xconv_kernel<<<dim3((unsigned)((n8 + BLK - 1)/BLK)), dim3(BLK), 0, stream>>>(
            P.nodeH, wsInt, xbf, (long)xelems);
      }
      q2_kernel<<<dim3((nb + 63)/64), dim3(BLK), 0, stream>>>(P, wsInt, wt, q2ws, nb);
      fused_v3<<<dim3(nb), dim3(BLK), 0, stream>>>(P, wsInt, wt, q2ws, xbf, 1);
    } else if (ws_size >= need1) {
      fused_v3<<<dim3(nb), dim3(BLK), 0, stream>>>(P, wsInt, wt, nullptr, nullptr, 0);
    } else {
      fused_mfma<<<dim3(nb), dim3(BLK), 0, stream>>>(P, wsInt, wt);
    }
  } else {
    fused_scalar<<<dim3(nb), dim3(BLK), 0, stream>>>(P, wsInt);
  }
}